// Round 1
// baseline (155.497 us; speedup 1.0000x reference)
//
#include <hip/hip_runtime.h>
#include <stdint.h>

#define B_  32
#define M_  1024
#define DF  128   // feature dim
#define ED  64    // embedding dim

typedef __attribute__((ext_vector_type(8))) short short8;   // 8 bf16 (4 VGPRs)
typedef __attribute__((ext_vector_type(4))) short short4v;  // 4 bf16 (2 VGPRs)
typedef __attribute__((ext_vector_type(4))) float floatx4;  // MFMA C/D

__device__ inline unsigned short f2bf(float f) {
    union { float f; unsigned u; } v; v.f = f;
    unsigned r = v.u + 0x7fffu + ((v.u >> 16) & 1u);
    return (unsigned short)(r >> 16);
}

__device__ inline short8 cvt8(float4 a, float4 b) {
    short8 s;
    s[0] = (short)f2bf(a.x); s[1] = (short)f2bf(a.y);
    s[2] = (short)f2bf(a.z); s[3] = (short)f2bf(a.w);
    s[4] = (short)f2bf(b.x); s[5] = (short)f2bf(b.y);
    s[6] = (short)f2bf(b.z); s[7] = (short)f2bf(b.w);
    return s;
}

__device__ inline void load_lds16(const void* g, void* l) {
    __builtin_amdgcn_global_load_lds(
        (const __attribute__((address_space(1))) unsigned int*)g,
        (__attribute__((address_space(3))) unsigned int*)l, 16, 0, 0);
}

// ================================================================ MAIN PATH
// ---------------------------------------------------------------- fused build:
//  E(fp32) -> S(bf16, stored transposed = identical since S symmetric),
//  dinv, and Xt = (dinv_n * X)^T for this block's own 64 rows.
__global__ __launch_bounds__(256) void build_fused_kernel(
    const float* __restrict__ E, const float* __restrict__ X,
    unsigned short* __restrict__ S, float* __restrict__ dinv,
    unsigned short* __restrict__ Xt) {
    int mt2 = blockIdx.x, b = blockIdx.y;     // 64-row strip
    int t = threadIdx.x;
    int w = t >> 6, lane = t & 63, quad = lane >> 4, lc = lane & 15;
    int m0 = mt2 * 64;

    __shared__ unsigned short sEn[128 * 72];  // staged E chunk (bf16)
    __shared__ unsigned short sOt[128 * 72];  // S^T tile [n_loc][m_loc]; reused as sT
    __shared__ float sDinv[64];

    const float* Eb = E + (size_t)b * M_ * ED;
    unsigned short* Sg = S + ((size_t)b << 20);
    int base_m = m0 + w * 16;

    // A-fragments: rows base_m + lc, cast fp32 -> bf16 in flight
    short8 afr[2];
    for (int ks = 0; ks < 2; ++ks) {
        const float* p = Eb + (size_t)(base_m + lc) * ED + ks * 32 + quad * 8;
        afr[ks] = cvt8(*(const float4*)p, *(const float4*)(p + 4));
    }
    floatx4 rsum = (floatx4){0.f, 0.f, 0.f, 0.f};

    for (int nc = 0; nc < 8; ++nc) {
        __syncthreads();
        // stage 128 n-rows x 64 fp32 -> bf16 LDS (reg-staged cast)
        for (int it = 0; it < 4; ++it) {
            int c = t + 256 * it;             // 1024 = 128 rows x 8
            int row = c >> 3, off = (c & 7) * 8;
            const float* p = Eb + (size_t)(nc * 128 + row) * ED + off;
            *(short8*)(&sEn[row * 72 + off]) = cvt8(*(const float4*)p, *(const float4*)(p + 4));
        }
        __syncthreads();
        for (int nt = 0; nt < 8; ++nt) {
            short8 b0 = *(const short8*)(&sEn[(nt * 16 + lc) * 72 + quad * 8]);
            short8 b1 = *(const short8*)(&sEn[(nt * 16 + lc) * 72 + 32 + quad * 8]);
            floatx4 s = (floatx4){0.f, 0.f, 0.f, 0.f};
            s = __builtin_amdgcn_mfma_f32_16x16x32_bf16(afr[0], b0, s, 0, 0, 0);
            s = __builtin_amdgcn_mfma_f32_16x16x32_bf16(afr[1], b1, s, 0, 0, 0);
            int nloc = nt * 16 + lc;
            int n = nc * 128 + nloc;
            short4v pk;
            for (int r = 0; r < 4; ++r) {
                int m = base_m + quad * 4 + r;
                float v = fmaxf(s[r], 0.f);
                if (m == n) v += 1.0f;
                rsum[r] += v;
                pk[r] = (short)f2bf(v);
            }
            // transposed: lane's 4 m-rows are contiguous -> one 8B LDS write
            *(short4v*)(&sOt[nloc * 72 + w * 16 + quad * 4]) = pk;
        }
        __syncthreads();
        // cooperative vectorized store of S^T strip: 128 n-rows x 64 m (16KB)
        for (int it = 0; it < 4; ++it) {
            int c = t + 256 * it;             // 1024 = 128 rows x 8
            int row = c >> 3, off = (c & 7) * 8;
            *(short8*)(Sg + (size_t)(nc * 128 + row) * M_ + m0 + off) =
                *(const short8*)(&sOt[row * 72 + off]);
        }
    }
    // dinv for own 64 rows
    for (int r = 0; r < 4; ++r) {
        float v = rsum[r];
        v += __shfl_xor(v, 1, 16);
        v += __shfl_xor(v, 2, 16);
        v += __shfl_xor(v, 4, 16);
        v += __shfl_xor(v, 8, 16);
        if (lc == 0) {
            float dvv = rsqrtf(v);
            int mloc = w * 16 + quad * 4 + r;
            sDinv[mloc] = dvv;
            dinv[b * M_ + m0 + mloc] = dvv;
        }
    }
    __syncthreads();                          // S-store reads of sOt done; sDinv ready
    // tscale: Xt[b][d][m0..m0+64) = bf16(dinv_n * X)^T, reuse sOt as sT[128 d][72]
    {
        int nloc = t >> 5;                    // 0..7
        int d4 = (t & 31) * 4;
        for (int pass = 0; pass < 8; ++pass) {
            int n = pass * 8 + nloc;          // local row 0..63
            float sc = sDinv[n];
            float4 v = *(const float4*)(X + (size_t)(b * M_ + m0 + n) * DF + d4);
            sOt[(d4 + 0) * 72 + n] = f2bf(v.x * sc);
            sOt[(d4 + 1) * 72 + n] = f2bf(v.y * sc);
            sOt[(d4 + 2) * 72 + n] = f2bf(v.z * sc);
            sOt[(d4 + 3) * 72 + n] = f2bf(v.w * sc);
        }
    }
    __syncthreads();
    for (int it = 0; it < 4; ++it) {
        int c = t + 256 * it;                 // 1024 = 128 d-rows x 8
        int d = c >> 3, off = (c & 7) * 8;
        *(short8*)(Xt + (size_t)(b * DF + d) * M_ + m0 + off) =
            *(const short8*)(&sOt[d * 72 + off]);
    }
}

// ---------------------------------------------------------------- GEMM layer (m97-style)
// Z[m][d] = sum_n S[m][n] * Pt[d][n]; Y = dinv_m*Z; H = relu(Y @ W^T)
// W is fp32 here; cast happens during epilogue LDS staging.
// MODE 1: OutT[b][o][m] = bf16(dinv_m * H)  (next layer's Pt)
// MODE 2: OutF[m][o]    = fp32(H), repacked through LDS for float4 stores
template <int MODE>
__global__ __launch_bounds__(256) void gemm_kernel(
    const unsigned short* __restrict__ S,
    const unsigned short* __restrict__ Pt,    // [b][128 d][1024 n] bf16
    const float* __restrict__ Wf,             // [128 o][128 i] fp32
    const float* __restrict__ dinv,
    unsigned short* __restrict__ OutT,
    float* __restrict__ OutF) {
    int bx = blockIdx.x, b = blockIdx.y;      // 64 m x 128 d tile
    int m0 = bx * 64;
    int t = threadIdx.x;
    int w = t >> 6, lane = t & 63, quad = lane >> 4, lc = lane & 15;
    int wr = w & 1, wc = w >> 1;              // wave: 32 m x 64 d quadrant

    // main: sA [64][64] u16 flat (8KB) | sB [128][64] u16 flat (16KB)
    // epi : sY [64][136] (17.4KB)      | sW/sT [128][136] (34.8KB)
    // MODE2 epi: sF [64][132] fp32 (33.8KB)
    __shared__ unsigned short lds[26112];     // 52,224 B
    unsigned short* sA = lds;
    unsigned short* sB = lds + 4096;
    unsigned short* sY = lds;                 // 64*136 = 8704
    unsigned short* sW = lds + 8704;          // 128*136 = 17408

    const unsigned short* Sg = S + ((size_t)b << 20);
    const unsigned short* Pb = Pt + (size_t)b * DF * M_;

    floatx4 acc[2][4];
    for (int i = 0; i < 2; ++i)
        for (int j = 0; j < 4; ++j) acc[i][j] = (floatx4){0.f, 0.f, 0.f, 0.f};

    for (int nc = 0; nc < 16; ++nc) {         // BK = 64
        __syncthreads();
        // stage sA: 64 rows x 64 n = 8KB -> 2 rounds of 256 lanes x 16B
        for (int r = 0; r < 2; ++r) {
            int te = r * 256 + w * 64 + lane;
            const void* gp = Sg + (size_t)(m0 + (te >> 3)) * M_ + nc * 64 + (te & 7) * 8;
            load_lds16(gp, (char*)sA + (r * 256 + w * 64) * 16);
        }
        // stage sB: 128 rows x 64 n = 16KB -> 4 rounds
        for (int r = 0; r < 4; ++r) {
            int te = r * 256 + w * 64 + lane;
            const void* gp = Pb + (size_t)(te >> 3) * M_ + nc * 64 + (te & 7) * 8;
            load_lds16(gp, (char*)sB + (r * 256 + w * 64) * 16);
        }
        __syncthreads();
        for (int ks = 0; ks < 2; ++ks) {
            short8 afr[2], bfr[4];
            for (int i = 0; i < 2; ++i)
                afr[i] = *(const short8*)(&sA[(wr * 32 + i * 16 + lc) * 64 + ks * 32 + quad * 8]);
            for (int j = 0; j < 4; ++j)
                bfr[j] = *(const short8*)(&sB[(wc * 64 + j * 16 + lc) * 64 + ks * 32 + quad * 8]);
            for (int i = 0; i < 2; ++i)
                for (int j = 0; j < 4; ++j)
                    acc[i][j] = __builtin_amdgcn_mfma_f32_16x16x32_bf16(afr[i], bfr[j], acc[i][j], 0, 0, 0);
        }
    }

    // ---- epilogue
    float dv[2][4];
    for (int i = 0; i < 2; ++i)
        for (int r = 0; r < 4; ++r)
            dv[i][r] = dinv[b * M_ + m0 + wr * 32 + i * 16 + quad * 4 + r];
    __syncthreads();                          // main-loop LDS reads done
    for (int i = 0; i < 2; ++i)
        for (int j = 0; j < 4; ++j) {
            int mrow = wr * 32 + i * 16 + quad * 4;
            int col = wc * 64 + j * 16 + lc;
            for (int r = 0; r < 4; ++r)
                sY[(mrow + r) * 136 + col] = f2bf(acc[i][j][r] * dv[i][r]);
        }
    // W (fp32): 128 x 128 -> bf16 LDS, 8 rounds of 256 x (8 floats)
    for (int it = 0; it < 8; ++it) {
        int c = t + 256 * it;
        int row = c >> 4, off = (c & 15) * 8;
        const float* p = Wf + row * DF + off;
        *(short8*)(&sW[row * 136 + off]) = cvt8(*(const float4*)p, *(const float4*)(p + 4));
    }
    __syncthreads();
    floatx4 accH[2][4];
    for (int i = 0; i < 2; ++i)
        for (int j = 0; j < 4; ++j) accH[i][j] = (floatx4){0.f, 0.f, 0.f, 0.f};
    for (int ks = 0; ks < 4; ++ks) {
        short8 afr[2], bfr[4];
        for (int i = 0; i < 2; ++i)
            afr[i] = *(const short8*)(&sY[(wr * 32 + i * 16 + lc) * 136 + ks * 32 + quad * 8]);
        for (int j = 0; j < 4; ++j)
            bfr[j] = *(const short8*)(&sW[(wc * 64 + j * 16 + lc) * 136 + ks * 32 + quad * 8]);
        for (int i = 0; i < 2; ++i)
            for (int j = 0; j < 4; ++j)
                accH[i][j] = __builtin_amdgcn_mfma_f32_16x16x32_bf16(afr[i], bfr[j], accH[i][j], 0, 0, 0);
    }
    if (MODE == 2) {
        __syncthreads();                      // sY/sW reads done; reuse as fp32 sF[64][132]
        float* sF = (float*)lds;
        for (int i = 0; i < 2; ++i)
            for (int j = 0; j < 4; ++j) {
                int mrow = wr * 32 + i * 16 + quad * 4;
                int col = wc * 64 + j * 16 + lc;
                for (int r = 0; r < 4; ++r)
                    sF[(mrow + r) * 132 + col] = fmaxf(accH[i][j][r], 0.f);
            }
        __syncthreads();
        float* Ob = OutF + ((size_t)b * M_ + m0) * DF;
        for (int it = 0; it < 8; ++it) {
            int c = t + 256 * it;             // 2048 = 64 rows x 32 float4
            int row = c >> 5, off = (c & 31) * 4;
            *(float4*)(Ob + (size_t)row * DF + off) = *(const float4*)(&sF[row * 132 + off]);
        }
    } else {
        __syncthreads();                      // sW reads done; reuse as sT [128 o][72]
        unsigned short* sT = sW;
        for (int i = 0; i < 2; ++i)
            for (int j = 0; j < 4; ++j) {
                int mrow = wr * 32 + i * 16 + quad * 4;
                int col = wc * 64 + j * 16 + lc;
                short4v pk;
                for (int r = 0; r < 4; ++r)
                    pk[r] = (short)f2bf(fmaxf(accH[i][j][r], 0.f) * dv[i][r]);
                *(short4v*)(&sT[col * 72 + mrow]) = pk;   // 8B write, mrow % 4 == 0
            }
        __syncthreads();
        for (int it = 0; it < 4; ++it) {
            int c = t + 256 * it;             // 1024 = 128 o-rows x 8
            int o = c >> 3, off = (c & 7) * 8;
            *(short8*)(OutT + (size_t)(b * DF + o) * M_ + m0 + off) =
                *(const short8*)(&sT[o * 72 + off]);
        }
    }
}

// ================================================================ fallback path (round-1, passed)
__global__ __launch_bounds__(256) void cast_kernel(
    const float* __restrict__ E, const float* __restrict__ W1,
    const float* __restrict__ W2, unsigned short* __restrict__ Ebf,
    unsigned short* __restrict__ W1bf, unsigned short* __restrict__ W2bf) {
    const int NE = B_ * M_ * ED;          // 2,097,152
    const int NW = DF * DF;               // 16,384
    int idx = (blockIdx.x * 256 + threadIdx.x) * 4;
    const float* src; unsigned short* dst; int off;
    if (idx < NE)            { src = E;  dst = Ebf;  off = idx; }
    else if (idx < NE + NW)  { src = W1; dst = W1bf; off = idx - NE; }
    else                     { src = W2; dst = W2bf; off = idx - NE - NW; }
    float4 v = *(const float4*)(src + off);
    ushort4 o;
    o.x = f2bf(v.x); o.y = f2bf(v.y); o.z = f2bf(v.z); o.w = f2bf(v.w);
    *(ushort4*)(dst + off) = o;
}

__global__ __launch_bounds__(256) void degree_kernel(
    const unsigned short* __restrict__ Ebf, float* __restrict__ dinv) {
    int mt = blockIdx.x, b = blockIdx.y;
    int t = threadIdx.x;
    int w = t >> 6, lane = t & 63, quad = lane >> 4, lc = lane & 15;
    __shared__ unsigned short sEn[128][72];
    const unsigned short* Eb = Ebf + (size_t)b * M_ * ED;
    short8 afr[2][2];
    for (int i = 0; i < 2; ++i) {
        int row = mt * 128 + w * 32 + i * 16 + lc;
        for (int ks = 0; ks < 2; ++ks)
            afr[i][ks] = *(const short8*)(Eb + (size_t)row * ED + ks * 32 + quad * 8);
    }
    floatx4 rsum[2];
    rsum[0] = (floatx4){0.f,0.f,0.f,0.f};
    rsum[1] = (floatx4){0.f,0.f,0.f,0.f};
    for (int nc = 0; nc < 8; ++nc) {
        __syncthreads();
        for (int it = 0; it < 4; ++it) {
            int c = t + 256 * it;
            int row = c >> 3, off = (c & 7) * 8;
            *(short8*)(&sEn[row][off]) =
                *(const short8*)(Eb + (size_t)(nc * 128 + row) * ED + off);
        }
        __syncthreads();
        for (int nt = 0; nt < 8; ++nt) {
            short8 b0 = *(const short8*)(&sEn[nt * 16 + lc][quad * 8]);
            short8 b1 = *(const short8*)(&sEn[nt * 16 + lc][32 + quad * 8]);
            for (int i = 0; i < 2; ++i) {
                floatx4 s = (floatx4){0.f,0.f,0.f,0.f};
                s = __builtin_amdgcn_mfma_f32_16x16x32_bf16(afr[i][0], b0, s, 0, 0, 0);
                s = __builtin_amdgcn_mfma_f32_16x16x32_bf16(afr[i][1], b1, s, 0, 0, 0);
                for (int r = 0; r < 4; ++r) rsum[i][r] += fmaxf(s[r], 0.f);
            }
        }
    }
    for (int i = 0; i < 2; ++i)
        for (int r = 0; r < 4; ++r) {
            float v = rsum[i][r];
            v += __shfl_xor(v, 1, 16);
            v += __shfl_xor(v, 2, 16);
            v += __shfl_xor(v, 4, 16);
            v += __shfl_xor(v, 8, 16);
            if (lc == 0) {
                int row = mt * 128 + w * 32 + i * 16 + quad * 4 + r;
                dinv[b * M_ + row] = rsqrtf(1.0f + v);
            }
        }
}

__global__ __launch_bounds__(256) void tscale128_kernel(
    const float* __restrict__ X, const float* __restrict__ dinv,
    unsigned short* __restrict__ Xt) {
    int mt = blockIdx.x, b = blockIdx.y;
    int t = threadIdx.x;
    __shared__ unsigned short sT[128][136];
    int nloc = t >> 5;
    int d4 = (t & 31) * 4;
    for (int pass = 0; pass < 16; ++pass) {
        int n = pass * 8 + nloc;
        int grow = b * M_ + mt * 128 + n;
        float sc = dinv[grow];
        float4 v = *(const float4*)(X + (size_t)grow * DF + d4);
        sT[d4 + 0][n] = f2bf(v.x * sc);
        sT[d4 + 1][n] = f2bf(v.y * sc);
        sT[d4 + 2][n] = f2bf(v.z * sc);
        sT[d4 + 3][n] = f2bf(v.w * sc);
    }
    __syncthreads();
    for (int it = 0; it < 8; ++it) {
        int c = t + 256 * it;
        int d = c >> 4, off = (c & 15) * 8;
        *(short8*)(Xt + (size_t)(b * DF + d) * M_ + mt * 128 + off) =
            *(const short8*)(&sT[d][off]);
    }
}

template <int MODE>
__global__ __launch_bounds__(256) void gcn_kernel(
    const unsigned short* __restrict__ Ebf,
    const unsigned short* __restrict__ Pt,
    const unsigned short* __restrict__ Wbf,
    const float* __restrict__ dinv,
    unsigned short* __restrict__ OutT,
    float* __restrict__ OutF) {
    int mt = blockIdx.x, b = blockIdx.y;
    int t = threadIdx.x;
    int w = t >> 6, lane = t & 63, quad = lane >> 4, lc = lane & 15;
    int wr = w & 1, wc = w >> 1;
    __shared__ unsigned short sEn[128][72];
    __shared__ unsigned short sS[128][136];
    __shared__ unsigned short sPW[128][136];
    const unsigned short* Eb = Ebf + (size_t)b * M_ * ED;
    short8 ae[4][2];
    for (int i = 0; i < 4; ++i) {
        int row = mt * 128 + wr * 64 + i * 16 + lc;
        for (int ks = 0; ks < 2; ++ks)
            ae[i][ks] = *(const short8*)(Eb + (size_t)row * ED + ks * 32 + quad * 8);
    }
    floatx4 accZ[4][4];
    for (int i = 0; i < 4; ++i)
        for (int j = 0; j < 4; ++j) accZ[i][j] = (floatx4){0.f,0.f,0.f,0.f};
    for (int nc = 0; nc < 8; ++nc) {
        __syncthreads();
        for (int it = 0; it < 4; ++it) {
            int c = t + 256 * it;
            int row = c >> 3, off = (c & 7) * 8;
            *(short8*)(&sEn[row][off]) =
                *(const short8*)(Eb + (size_t)(nc * 128 + row) * ED + off);
        }
        for (int it = 0; it < 8; ++it) {
            int c = t + 256 * it;
            int drow = c >> 4, off = (c & 15) * 8;
            *(short8*)(&sPW[drow][off]) =
                *(const short8*)(Pt + (size_t)(b * DF + drow) * M_ + nc * 128 + off);
        }
        __syncthreads();
        for (int jt = 0; jt < 4; ++jt) {
            int ncol = wc * 64 + jt * 16;
            short8 b0 = *(const short8*)(&sEn[ncol + lc][quad * 8]);
            short8 b1 = *(const short8*)(&sEn[ncol + lc][32 + quad * 8]);
            for (int i = 0; i < 4; ++i) {
                floatx4 s = (floatx4){0.f,0.f,0.f,0.f};
                s = __builtin_amdgcn_mfma_f32_16x16x32_bf16(ae[i][0], b0, s, 0, 0, 0);
                s = __builtin_amdgcn_mfma_f32_16x16x32_bf16(ae[i][1], b1, s, 0, 0, 0);
                int mrow = wr * 64 + i * 16 + quad * 4;
                for (int r = 0; r < 4; ++r) {
                    float v = fmaxf(s[r], 0.f);
                    if (mt == nc && (mrow + r) == (ncol + lc)) v += 1.0f;
                    sS[mrow + r][ncol + lc] = f2bf(v);
                }
            }
        }
        __syncthreads();
        for (int ks = 0; ks < 4; ++ks) {
            short8 afr[4];
            for (int i = 0; i < 4; ++i)
                afr[i] = *(const short8*)(&sS[wr * 64 + i * 16 + lc][ks * 32 + quad * 8]);
            for (int j = 0; j < 4; ++j) {
                short8 bfr = *(const short8*)(&sPW[wc * 64 + j * 16 + lc][ks * 32 + quad * 8]);
                for (int i = 0; i < 4; ++i)
                    accZ[i][j] = __builtin_amdgcn_mfma_f32_16x16x32_bf16(afr[i], bfr, accZ[i][j], 0, 0, 0);
            }
        }
    }
    float dv[4][4];
    for (int i = 0; i < 4; ++i)
        for (int r = 0; r < 4; ++r)
            dv[i][r] = dinv[b * M_ + mt * 128 + wr * 64 + i * 16 + quad * 4 + r];
    __syncthreads();
    for (int i = 0; i < 4; ++i)
        for (int j = 0; j < 4; ++j) {
            int mrow = wr * 64 + i * 16 + quad * 4;
            int col = wc * 64 + j * 16 + lc;
            for (int r = 0; r < 4; ++r)
                sS[mrow + r][col] = f2bf(accZ[i][j][r] * dv[i][r]);
        }
    for (int it = 0; it < 8; ++it) {
        int c = t + 256 * it;
        int row = c >> 4, off = (c & 15) * 8;
        *(short8*)(&sPW[row][off]) = *(const short8*)(Wbf + row * DF + off);
    }
    __syncthreads();
    floatx4 accH[4][4];
    for (int i = 0; i < 4; ++i)
        for (int j = 0; j < 4; ++j) accH[i][j] = (floatx4){0.f,0.f,0.f,0.f};
    for (int ks = 0; ks < 4; ++ks) {
        short8 afr[4], bfr[4];
        for (int i = 0; i < 4; ++i)
            afr[i] = *(const short8*)(&sS[wr * 64 + i * 16 + lc][ks * 32 + quad * 8]);
        for (int j = 0; j < 4; ++j)
            bfr[j] = *(const short8*)(&sPW[wc * 64 + j * 16 + lc][ks * 32 + quad * 8]);
        for (int i = 0; i < 4; ++i)
            for (int j = 0; j < 4; ++j)
                accH[i][j] = __builtin_amdgcn_mfma_f32_16x16x32_bf16(afr[i], bfr[j], accH[i][j], 0, 0, 0);
    }
    if (MODE == 2) {
        float* Ob = OutF + ((size_t)b * M_ + mt * 128) * DF;
        for (int i = 0; i < 4; ++i)
            for (int j = 0; j < 4; ++j) {
                int mrow = wr * 64 + i * 16 + quad * 4;
                int col = wc * 64 + j * 16 + lc;
                for (int r = 0; r < 4; ++r)
                    Ob[(size_t)(mrow + r) * DF + col] = fmaxf(accH[i][j][r], 0.f);
            }
    } else {
        __syncthreads();
        for (int i = 0; i < 4; ++i)
            for (int j = 0; j < 4; ++j) {
                int mrow = wr * 64 + i * 16 + quad * 4;
                int col = wc * 64 + j * 16 + lc;
                for (int r = 0; r < 4; ++r)
                    sS[col][mrow + r] = f2bf(fmaxf(accH[i][j][r], 0.f) * dv[i][r]);
            }
        __syncthreads();
        unsigned short* Ob = OutT + (size_t)b * DF * M_ + mt * 128;
        for (int it = 0; it < 8; ++it) {
            int c = t + 256 * it;
            int orow = c >> 4, off = (c & 15) * 8;
            *(short8*)(Ob + (size_t)orow * M_ + off) = *(const short8*)(&sS[orow][off]);
        }
    }
}

// ---------------------------------------------------------------- launch
extern "C" void kernel_launch(void* const* d_in, const int* in_sizes, int n_in,
                              void* d_out, int out_size, void* d_ws, size_t ws_size,
                              hipStream_t stream) {
    (void)in_sizes; (void)n_in; (void)out_size;
    const float* X  = (const float*)d_in[0];
    const float* E  = (const float*)d_in[1];
    const float* W1 = (const float*)d_in[2];
    const float* W2 = (const float*)d_in[3];
    float* out = (float*)d_out;

    char* ws = (char*)d_ws;
    unsigned short* Ebf  = (unsigned short*)(ws);
    unsigned short* W1bf = (unsigned short*)(ws + 4194304);
    unsigned short* W2bf = (unsigned short*)(ws + 4227072);
    float*          dinv = (float*)(ws + 4259840);
    unsigned short* Xt   = (unsigned short*)(ws + 4390912);
    unsigned short* Ht   = (unsigned short*)(ws + 12779520);
    unsigned short* Smat = (unsigned short*)(ws + 21168128);
    const size_t NEED = 21168128ull + 67108864ull;   // 88,276,992 B

    if (ws_size >= NEED) {
        build_fused_kernel<<<dim3(16, 32), 256, 0, stream>>>(E, X, Smat, dinv, Xt);
        gemm_kernel<1><<<dim3(16, 32), 256, 0, stream>>>(Smat, Xt, W1, dinv, Ht, nullptr);
        gemm_kernel<2><<<dim3(16, 32), 256, 0, stream>>>(Smat, Ht, W2, dinv, nullptr, out);
    } else {
        cast_kernel<<<2080, 256, 0, stream>>>(E, W1, W2, Ebf, W1bf, W2bf);
        degree_kernel<<<dim3(8, 32), 256, 0, stream>>>(Ebf, dinv);
        tscale128_kernel<<<dim3(8, 32), 256, 0, stream>>>(X, dinv, Xt);
        gcn_kernel<1><<<dim3(8, 32), 256, 0, stream>>>(Ebf, Xt, W1bf, dinv, Ht, nullptr);
        gcn_kernel<2><<<dim3(8, 32), 256, 0, stream>>>(Ebf, Ht, W2bf, dinv, nullptr, out);
    }
}

// Round 2
// 154.108 us; speedup vs baseline: 1.0090x; 1.0090x over previous
//
#include <hip/hip_runtime.h>
#include <stdint.h>

#define B_  32
#define M_  1024
#define DF  128   // feature dim
#define ED  64    // embedding dim

typedef __attribute__((ext_vector_type(8))) short short8;   // 8 bf16 (4 VGPRs)
typedef __attribute__((ext_vector_type(4))) short short4v;  // 4 bf16 (2 VGPRs)
typedef __attribute__((ext_vector_type(4))) float floatx4;  // MFMA C/D

__device__ inline unsigned short f2bf(float f) {
    union { float f; unsigned u; } v; v.f = f;
    unsigned r = v.u + 0x7fffu + ((v.u >> 16) & 1u);
    return (unsigned short)(r >> 16);
}

__device__ inline short8 cvt8(float4 a, float4 b) {
    short8 s;
    s[0] = (short)f2bf(a.x); s[1] = (short)f2bf(a.y);
    s[2] = (short)f2bf(a.z); s[3] = (short)f2bf(a.w);
    s[4] = (short)f2bf(b.x); s[5] = (short)f2bf(b.y);
    s[6] = (short)f2bf(b.z); s[7] = (short)f2bf(b.w);
    return s;
}

// ================================================================ MAIN PATH
// block remap: XCD g = lin%8 owns sub-graphs b in [4g, 4g+4) -> E/Pt stay L2-resident
__device__ inline void remap_block(int& b, int& mt2) {
    int lin = blockIdx.y * 16 + blockIdx.x;
    int g = lin & 7, kk = lin >> 3;
    b = g * 4 + (kk >> 4);
    mt2 = kk & 15;
}

// ---------------------------------------------------------------- prep:
//  dinv (full rowsums of relu(EE^T)+I via MFMA), Ebf (bf16 cast of E),
//  Xt = (dinv_n * X)^T for this block's 64 rows. No S materialization.
__global__ __launch_bounds__(256) void prep_kernel(
    const float* __restrict__ E, const float* __restrict__ X,
    unsigned short* __restrict__ Ebf, float* __restrict__ dinv,
    unsigned short* __restrict__ Xt) {
    int b, mt2; remap_block(b, mt2);
    int m0 = mt2 * 64;
    int t = threadIdx.x;
    int w = t >> 6, lane = t & 63, quad = lane >> 4, lc = lane & 15;

    __shared__ unsigned short sEn[128 * 72];  // staged E chunk (bf16); reused as sT
    __shared__ float sDinv[64];

    const float* Eb = E + (size_t)b * M_ * ED;
    unsigned short* Ebg = Ebf + (size_t)b * M_ * ED;
    int base_m = m0 + w * 16;

    // A-fragments: rows base_m + lc, cast fp32 -> bf16 in flight
    short8 afr[2];
    for (int ks = 0; ks < 2; ++ks) {
        const float* p = Eb + (size_t)(base_m + lc) * ED + ks * 32 + quad * 8;
        afr[ks] = cvt8(*(const float4*)p, *(const float4*)(p + 4));
    }
    floatx4 rsum = (floatx4){0.f, 0.f, 0.f, 0.f};

    for (int nc = 0; nc < 8; ++nc) {
        __syncthreads();
        // stage 128 n-rows x 64 fp32 -> bf16 LDS (reg-staged cast)
        for (int it = 0; it < 4; ++it) {
            int c = t + 256 * it;             // 1024 = 128 rows x 8
            int row = c >> 3, off = (c & 7) * 8;
            const float* p = Eb + (size_t)(nc * 128 + row) * ED + off;
            *(short8*)(&sEn[row * 72 + off]) = cvt8(*(const float4*)p, *(const float4*)(p + 4));
        }
        __syncthreads();
        // each block persists one chunk-half of Ebf (mt2 0..7 -> half 0, 8..15 -> half 1)
        if ((mt2 & 7) == nc) {
            int half = mt2 >> 3;
            for (int it = 0; it < 2; ++it) {
                int c = t + 256 * it;         // 512 = 64 rows x 8
                int row = half * 64 + (c >> 3), off = (c & 7) * 8;
                *(short8*)(Ebg + (size_t)(nc * 128 + row) * ED + off) =
                    *(const short8*)(&sEn[row * 72 + off]);
            }
        }
        for (int nt = 0; nt < 8; ++nt) {
            short8 b0 = *(const short8*)(&sEn[(nt * 16 + lc) * 72 + quad * 8]);
            short8 b1 = *(const short8*)(&sEn[(nt * 16 + lc) * 72 + 32 + quad * 8]);
            floatx4 s = (floatx4){0.f, 0.f, 0.f, 0.f};
            s = __builtin_amdgcn_mfma_f32_16x16x32_bf16(afr[0], b0, s, 0, 0, 0);
            s = __builtin_amdgcn_mfma_f32_16x16x32_bf16(afr[1], b1, s, 0, 0, 0);
            int n = nc * 128 + nt * 16 + lc;
            for (int r = 0; r < 4; ++r) {
                int m = base_m + quad * 4 + r;
                float v = fmaxf(s[r], 0.f);
                if (m == n) v += 1.0f;
                rsum[r] += v;
            }
        }
    }
    // dinv for own 64 rows
    for (int r = 0; r < 4; ++r) {
        float v = rsum[r];
        v += __shfl_xor(v, 1, 16);
        v += __shfl_xor(v, 2, 16);
        v += __shfl_xor(v, 4, 16);
        v += __shfl_xor(v, 8, 16);
        if (lc == 0) {
            float dvv = rsqrtf(v);
            int mloc = w * 16 + quad * 4 + r;
            sDinv[mloc] = dvv;
            dinv[b * M_ + m0 + mloc] = dvv;
        }
    }
    __syncthreads();                          // all sEn reads done; sDinv ready
    // tscale: Xt[b][d][m0..m0+64) = bf16(dinv_n * X)^T, reuse sEn as sT[128 d][72]
    {
        int nloc = t >> 5;                    // 0..7
        int d4 = (t & 31) * 4;
        for (int pass = 0; pass < 8; ++pass) {
            int n = pass * 8 + nloc;          // local row 0..63
            float sc = sDinv[n];
            float4 v = *(const float4*)(X + (size_t)(b * M_ + m0 + n) * DF + d4);
            sEn[(d4 + 0) * 72 + n] = f2bf(v.x * sc);
            sEn[(d4 + 1) * 72 + n] = f2bf(v.y * sc);
            sEn[(d4 + 2) * 72 + n] = f2bf(v.z * sc);
            sEn[(d4 + 3) * 72 + n] = f2bf(v.w * sc);
        }
    }
    __syncthreads();
    for (int it = 0; it < 4; ++it) {
        int c = t + 256 * it;                 // 1024 = 128 d-rows x 8
        int d = c >> 3, off = (c & 7) * 8;
        *(short8*)(Xt + (size_t)(b * DF + d) * M_ + m0 + off) =
            *(const short8*)(&sEn[d * 72 + off]);
    }
}

// ---------------------------------------------------------------- fused layer:
// per 128-n chunk: S_tile = relu(E_m E_n^T)+I (in LDS, recomputed), Z += S_tile @ Pt^T.
// Then Y = dinv_m*Z; H = relu(Y @ W^T).  W is fp32 (cast in epilogue staging).
// MODE 1: OutT[b][o][m] = bf16(dinv_m * H)   MODE 2: OutF[m][o] = fp32(H)
template <int MODE>
__global__ __launch_bounds__(256) void layer_kernel(
    const unsigned short* __restrict__ Ebf,   // [b][1024 n][64] bf16
    const unsigned short* __restrict__ Pt,    // [b][128 d][1024 n] bf16
    const float* __restrict__ Wf,             // [128 o][128 i] fp32
    const float* __restrict__ dinv,
    unsigned short* __restrict__ OutT,
    float* __restrict__ OutF) {
    int b, mt2; remap_block(b, mt2);
    int m0 = mt2 * 64;                        // 64 m-rows per block
    int t = threadIdx.x;
    int w = t >> 6, lane = t & 63, quad = lane >> 4, lc = lane & 15;
    int wr = w & 1, wc = w >> 1;              // wave: 32 m x (64 n or 64 d)

    // sEn [128][72] 18432B | sS [64][136] 17408B | sPW [128][136] 34816B = 70656B
    __shared__ unsigned short lds[35328];
    unsigned short* sEn = lds;
    unsigned short* sS  = lds + 9216;         // also sY in epilogue
    unsigned short* sPW = lds + 17920;        // also sW / sT in epilogue

    const unsigned short* Eb = Ebf + (size_t)b * M_ * ED;
    const unsigned short* Pb = Pt + (size_t)b * DF * M_;

    // E fragments for own m-rows (constant over nc)
    short8 ae[2][2];
    for (int i = 0; i < 2; ++i) {
        int row = m0 + wr * 32 + i * 16 + lc;
        for (int ks = 0; ks < 2; ++ks)
            ae[i][ks] = *(const short8*)(Eb + (size_t)row * ED + ks * 32 + quad * 8);
    }

    floatx4 acc[2][4];
    for (int i = 0; i < 2; ++i)
        for (int j = 0; j < 4; ++j) acc[i][j] = (floatx4){0.f, 0.f, 0.f, 0.f};

    for (int nc = 0; nc < 8; ++nc) {          // 128-n chunks
        __syncthreads();
        // stage sEn: 128 n-rows x 64 bf16 (16KB)
        for (int it = 0; it < 4; ++it) {
            int c = t + 256 * it;
            int row = c >> 3, off = (c & 7) * 8;
            *(short8*)(&sEn[row * 72 + off]) =
                *(const short8*)(Eb + (size_t)(nc * 128 + row) * ED + off);
        }
        // stage sPW: 128 d-rows x 128 n (32KB)
        for (int it = 0; it < 8; ++it) {
            int c = t + 256 * it;
            int drow = c >> 4, off = (c & 15) * 8;
            *(short8*)(&sPW[drow * 136 + off]) =
                *(const short8*)(Pb + (size_t)drow * M_ + nc * 128 + off);
        }
        __syncthreads();
        // S tile: 64 m x 128 n, each wave owns (wr: 32 m) x (wc: 64 n)
        for (int jt = 0; jt < 4; ++jt) {
            int ncol = wc * 64 + jt * 16;
            short8 b0 = *(const short8*)(&sEn[(ncol + lc) * 72 + quad * 8]);
            short8 b1 = *(const short8*)(&sEn[(ncol + lc) * 72 + 32 + quad * 8]);
            for (int i = 0; i < 2; ++i) {
                floatx4 s = (floatx4){0.f, 0.f, 0.f, 0.f};
                s = __builtin_amdgcn_mfma_f32_16x16x32_bf16(ae[i][0], b0, s, 0, 0, 0);
                s = __builtin_amdgcn_mfma_f32_16x16x32_bf16(ae[i][1], b1, s, 0, 0, 0);
                int mrow = wr * 32 + i * 16 + quad * 4;
                for (int r = 0; r < 4; ++r) {
                    float v = fmaxf(s[r], 0.f);
                    if (m0 + mrow + r == nc * 128 + ncol + lc) v += 1.0f;
                    sS[(mrow + r) * 136 + ncol + lc] = f2bf(v);
                }
            }
        }
        __syncthreads();
        // Z += S_tile @ Pt_tile^T  (K = 128 n)
        for (int ks = 0; ks < 4; ++ks) {
            short8 afr[2], bfr[4];
            for (int i = 0; i < 2; ++i)
                afr[i] = *(const short8*)(&sS[(wr * 32 + i * 16 + lc) * 136 + ks * 32 + quad * 8]);
            for (int j = 0; j < 4; ++j)
                bfr[j] = *(const short8*)(&sPW[(wc * 64 + j * 16 + lc) * 136 + ks * 32 + quad * 8]);
            for (int i = 0; i < 2; ++i)
                for (int j = 0; j < 4; ++j)
                    acc[i][j] = __builtin_amdgcn_mfma_f32_16x16x32_bf16(afr[i], bfr[j], acc[i][j], 0, 0, 0);
        }
    }

    // ---- epilogue (identical to verified gemm_kernel epilogue)
    float dv[2][4];
    for (int i = 0; i < 2; ++i)
        for (int r = 0; r < 4; ++r)
            dv[i][r] = dinv[b * M_ + m0 + wr * 32 + i * 16 + quad * 4 + r];
    __syncthreads();                          // main-loop LDS reads done
    unsigned short* sY = sS;                  // [64][136]
    unsigned short* sW = sPW;                 // [128][136]
    for (int i = 0; i < 2; ++i)
        for (int j = 0; j < 4; ++j) {
            int mrow = wr * 32 + i * 16 + quad * 4;
            int col = wc * 64 + j * 16 + lc;
            for (int r = 0; r < 4; ++r)
                sY[(mrow + r) * 136 + col] = f2bf(acc[i][j][r] * dv[i][r]);
        }
    // W (fp32): 128 x 128 -> bf16 LDS
    for (int it = 0; it < 8; ++it) {
        int c = t + 256 * it;
        int row = c >> 4, off = (c & 15) * 8;
        const float* p = Wf + row * DF + off;
        *(short8*)(&sW[row * 136 + off]) = cvt8(*(const float4*)p, *(const float4*)(p + 4));
    }
    __syncthreads();
    floatx4 accH[2][4];
    for (int i = 0; i < 2; ++i)
        for (int j = 0; j < 4; ++j) accH[i][j] = (floatx4){0.f, 0.f, 0.f, 0.f};
    for (int ks = 0; ks < 4; ++ks) {
        short8 afr[2], bfr[4];
        for (int i = 0; i < 2; ++i)
            afr[i] = *(const short8*)(&sY[(wr * 32 + i * 16 + lc) * 136 + ks * 32 + quad * 8]);
        for (int j = 0; j < 4; ++j)
            bfr[j] = *(const short8*)(&sW[(wc * 64 + j * 16 + lc) * 136 + ks * 32 + quad * 8]);
        for (int i = 0; i < 2; ++i)
            for (int j = 0; j < 4; ++j)
                accH[i][j] = __builtin_amdgcn_mfma_f32_16x16x32_bf16(afr[i], bfr[j], accH[i][j], 0, 0, 0);
    }
    if (MODE == 2) {
        __syncthreads();                      // reuse lds as fp32 sF[64][132]
        float* sF = (float*)lds;
        for (int i = 0; i < 2; ++i)
            for (int j = 0; j < 4; ++j) {
                int mrow = wr * 32 + i * 16 + quad * 4;
                int col = wc * 64 + j * 16 + lc;
                for (int r = 0; r < 4; ++r)
                    sF[(mrow + r) * 132 + col] = fmaxf(accH[i][j][r], 0.f);
            }
        __syncthreads();
        float* Ob = OutF + ((size_t)b * M_ + m0) * DF;
        for (int it = 0; it < 8; ++it) {
            int c = t + 256 * it;             // 2048 = 64 rows x 32 float4
            int row = c >> 5, off = (c & 31) * 4;
            *(float4*)(Ob + (size_t)row * DF + off) = *(const float4*)(&sF[row * 132 + off]);
        }
    } else {
        __syncthreads();                      // sW reads done; reuse as sT [128 o][72]
        unsigned short* sT = sW;
        for (int i = 0; i < 2; ++i)
            for (int j = 0; j < 4; ++j) {
                int mrow = wr * 32 + i * 16 + quad * 4;
                int col = wc * 64 + j * 16 + lc;
                short4v pk;
                for (int r = 0; r < 4; ++r)
                    pk[r] = (short)f2bf(fmaxf(accH[i][j][r], 0.f) * dv[i][r]);
                *(short4v*)(&sT[col * 72 + mrow]) = pk;   // 8B write, mrow % 4 == 0
            }
        __syncthreads();
        for (int it = 0; it < 4; ++it) {
            int c = t + 256 * it;             // 1024 = 128 o-rows x 8
            int o = c >> 3, off = (c & 7) * 8;
            *(short8*)(OutT + (size_t)(b * DF + o) * M_ + m0 + off) =
                *(const short8*)(&sT[o * 72 + off]);
        }
    }
}

// ================================================================ fallback path (verified earlier)
__global__ __launch_bounds__(256) void cast_kernel(
    const float* __restrict__ E, const float* __restrict__ W1,
    const float* __restrict__ W2, unsigned short* __restrict__ Ebf,
    unsigned short* __restrict__ W1bf, unsigned short* __restrict__ W2bf) {
    const int NE = B_ * M_ * ED;          // 2,097,152
    const int NW = DF * DF;               // 16,384
    int idx = (blockIdx.x * 256 + threadIdx.x) * 4;
    const float* src; unsigned short* dst; int off;
    if (idx < NE)            { src = E;  dst = Ebf;  off = idx; }
    else if (idx < NE + NW)  { src = W1; dst = W1bf; off = idx - NE; }
    else                     { src = W2; dst = W2bf; off = idx - NE - NW; }
    float4 v = *(const float4*)(src + off);
    ushort4 o;
    o.x = f2bf(v.x); o.y = f2bf(v.y); o.z = f2bf(v.z); o.w = f2bf(v.w);
    *(ushort4*)(dst + off) = o;
}

__global__ __launch_bounds__(256) void degree_kernel(
    const unsigned short* __restrict__ Ebf, float* __restrict__ dinv) {
    int mt = blockIdx.x, b = blockIdx.y;
    int t = threadIdx.x;
    int w = t >> 6, lane = t & 63, quad = lane >> 4, lc = lane & 15;
    __shared__ unsigned short sEn[128][72];
    const unsigned short* Eb = Ebf + (size_t)b * M_ * ED;
    short8 afr[2][2];
    for (int i = 0; i < 2; ++i) {
        int row = mt * 128 + w * 32 + i * 16 + lc;
        for (int ks = 0; ks < 2; ++ks)
            afr[i][ks] = *(const short8*)(Eb + (size_t)row * ED + ks * 32 + quad * 8);
    }
    floatx4 rsum[2];
    rsum[0] = (floatx4){0.f,0.f,0.f,0.f};
    rsum[1] = (floatx4){0.f,0.f,0.f,0.f};
    for (int nc = 0; nc < 8; ++nc) {
        __syncthreads();
        for (int it = 0; it < 4; ++it) {
            int c = t + 256 * it;
            int row = c >> 3, off = (c & 7) * 8;
            *(short8*)(&sEn[row][off]) =
                *(const short8*)(Eb + (size_t)(nc * 128 + row) * ED + off);
        }
        __syncthreads();
        for (int nt = 0; nt < 8; ++nt) {
            short8 b0 = *(const short8*)(&sEn[nt * 16 + lc][quad * 8]);
            short8 b1 = *(const short8*)(&sEn[nt * 16 + lc][32 + quad * 8]);
            for (int i = 0; i < 2; ++i) {
                floatx4 s = (floatx4){0.f,0.f,0.f,0.f};
                s = __builtin_amdgcn_mfma_f32_16x16x32_bf16(afr[i][0], b0, s, 0, 0, 0);
                s = __builtin_amdgcn_mfma_f32_16x16x32_bf16(afr[i][1], b1, s, 0, 0, 0);
                for (int r = 0; r < 4; ++r) rsum[i][r] += fmaxf(s[r], 0.f);
            }
        }
    }
    for (int i = 0; i < 2; ++i)
        for (int r = 0; r < 4; ++r) {
            float v = rsum[i][r];
            v += __shfl_xor(v, 1, 16);
            v += __shfl_xor(v, 2, 16);
            v += __shfl_xor(v, 4, 16);
            v += __shfl_xor(v, 8, 16);
            if (lc == 0) {
                int row = mt * 128 + w * 32 + i * 16 + quad * 4 + r;
                dinv[b * M_ + row] = rsqrtf(1.0f + v);
            }
        }
}

__global__ __launch_bounds__(256) void tscale128_kernel(
    const float* __restrict__ X, const float* __restrict__ dinv,
    unsigned short* __restrict__ Xt) {
    int mt = blockIdx.x, b = blockIdx.y;
    int t = threadIdx.x;
    __shared__ unsigned short sT[128][136];
    int nloc = t >> 5;
    int d4 = (t & 31) * 4;
    for (int pass = 0; pass < 16; ++pass) {
        int n = pass * 8 + nloc;
        int grow = b * M_ + mt * 128 + n;
        float sc = dinv[grow];
        float4 v = *(const float4*)(X + (size_t)grow * DF + d4);
        sT[d4 + 0][n] = f2bf(v.x * sc);
        sT[d4 + 1][n] = f2bf(v.y * sc);
        sT[d4 + 2][n] = f2bf(v.z * sc);
        sT[d4 + 3][n] = f2bf(v.w * sc);
    }
    __syncthreads();
    for (int it = 0; it < 8; ++it) {
        int c = t + 256 * it;
        int d = c >> 4, off = (c & 15) * 8;
        *(short8*)(Xt + (size_t)(b * DF + d) * M_ + mt * 128 + off) =
            *(const short8*)(&sT[d][off]);
    }
}

template <int MODE>
__global__ __launch_bounds__(256) void gcn_kernel(
    const unsigned short* __restrict__ Ebf,
    const unsigned short* __restrict__ Pt,
    const unsigned short* __restrict__ Wbf,
    const float* __restrict__ dinv,
    unsigned short* __restrict__ OutT,
    float* __restrict__ OutF) {
    int mt = blockIdx.x, b = blockIdx.y;
    int t = threadIdx.x;
    int w = t >> 6, lane = t & 63, quad = lane >> 4, lc = lane & 15;
    int wr = w & 1, wc = w >> 1;
    __shared__ unsigned short sEn[128][72];
    __shared__ unsigned short sS[128][136];
    __shared__ unsigned short sPW[128][136];
    const unsigned short* Eb = Ebf + (size_t)b * M_ * ED;
    short8 ae[4][2];
    for (int i = 0; i < 4; ++i) {
        int row = mt * 128 + wr * 64 + i * 16 + lc;
        for (int ks = 0; ks < 2; ++ks)
            ae[i][ks] = *(const short8*)(Eb + (size_t)row * ED + ks * 32 + quad * 8);
    }
    floatx4 accZ[4][4];
    for (int i = 0; i < 4; ++i)
        for (int j = 0; j < 4; ++j) accZ[i][j] = (floatx4){0.f,0.f,0.f,0.f};
    for (int nc = 0; nc < 8; ++nc) {
        __syncthreads();
        for (int it = 0; it < 4; ++it) {
            int c = t + 256 * it;
            int row = c >> 3, off = (c & 7) * 8;
            *(short8*)(&sEn[row][off]) =
                *(const short8*)(Eb + (size_t)(nc * 128 + row) * ED + off);
        }
        for (int it = 0; it < 8; ++it) {
            int c = t + 256 * it;
            int drow = c >> 4, off = (c & 15) * 8;
            *(short8*)(&sPW[drow][off]) =
                *(const short8*)(Pt + (size_t)(b * DF + drow) * M_ + nc * 128 + off);
        }
        __syncthreads();
        for (int jt = 0; jt < 4; ++jt) {
            int ncol = wc * 64 + jt * 16;
            short8 b0 = *(const short8*)(&sEn[ncol + lc][quad * 8]);
            short8 b1 = *(const short8*)(&sEn[ncol + lc][32 + quad * 8]);
            for (int i = 0; i < 4; ++i) {
                floatx4 s = (floatx4){0.f,0.f,0.f,0.f};
                s = __builtin_amdgcn_mfma_f32_16x16x32_bf16(ae[i][0], b0, s, 0, 0, 0);
                s = __builtin_amdgcn_mfma_f32_16x16x32_bf16(ae[i][1], b1, s, 0, 0, 0);
                int mrow = wr * 64 + i * 16 + quad * 4;
                for (int r = 0; r < 4; ++r) {
                    float v = fmaxf(s[r], 0.f);
                    if (mt == nc && (mrow + r) == (ncol + lc)) v += 1.0f;
                    sS[mrow + r][ncol + lc] = f2bf(v);
                }
            }
        }
        __syncthreads();
        for (int ks = 0; ks < 4; ++ks) {
            short8 afr[4];
            for (int i = 0; i < 4; ++i)
                afr[i] = *(const short8*)(&sS[wr * 64 + i * 16 + lc][ks * 32 + quad * 8]);
            for (int j = 0; j < 4; ++j) {
                short8 bfr = *(const short8*)(&sPW[wc * 64 + j * 16 + lc][ks * 32 + quad * 8]);
                for (int i = 0; i < 4; ++i)
                    accZ[i][j] = __builtin_amdgcn_mfma_f32_16x16x32_bf16(afr[i], bfr, accZ[i][j], 0, 0, 0);
            }
        }
    }
    float dv[4][4];
    for (int i = 0; i < 4; ++i)
        for (int r = 0; r < 4; ++r)
            dv[i][r] = dinv[b * M_ + mt * 128 + wr * 64 + i * 16 + quad * 4 + r];
    __syncthreads();
    for (int i = 0; i < 4; ++i)
        for (int j = 0; j < 4; ++j) {
            int mrow = wr * 64 + i * 16 + quad * 4;
            int col = wc * 64 + j * 16 + lc;
            for (int r = 0; r < 4; ++r)
                sS[mrow + r][col] = f2bf(accZ[i][j][r] * dv[i][r]);
        }
    for (int it = 0; it < 8; ++it) {
        int c = t + 256 * it;
        int row = c >> 4, off = (c & 15) * 8;
        *(short8*)(&sPW[row][off]) = *(const short8*)(Wbf + row * DF + off);
    }
    __syncthreads();
    floatx4 accH[4][4];
    for (int i = 0; i < 4; ++i)
        for (int j = 0; j < 4; ++j) accH[i][j] = (floatx4){0.f,0.f,0.f,0.f};
    for (int ks = 0; ks < 4; ++ks) {
        short8 afr[4], bfr[4];
        for (int i = 0; i < 4; ++i)
            afr[i] = *(const short8*)(&sS[wr * 64 + i * 16 + lc][ks * 32 + quad * 8]);
        for (int j = 0; j < 4; ++j)
            bfr[j] = *(const short8*)(&sPW[wc * 64 + j * 16 + lc][ks * 32 + quad * 8]);
        for (int i = 0; i < 4; ++i)
            for (int j = 0; j < 4; ++j)
                accH[i][j] = __builtin_amdgcn_mfma_f32_16x16x32_bf16(afr[i], bfr[j], accH[i][j], 0, 0, 0);
    }
    if (MODE == 2) {
        float* Ob = OutF + ((size_t)b * M_ + mt * 128) * DF;
        for (int i = 0; i < 4; ++i)
            for (int j = 0; j < 4; ++j) {
                int mrow = wr * 64 + i * 16 + quad * 4;
                int col = wc * 64 + j * 16 + lc;
                for (int r = 0; r < 4; ++r)
                    Ob[(size_t)(mrow + r) * DF + col] = fmaxf(accH[i][j][r], 0.f);
            }
    } else {
        __syncthreads();
        for (int i = 0; i < 4; ++i)
            for (int j = 0; j < 4; ++j) {
                int mrow = wr * 64 + i * 16 + quad * 4;
                int col = wc * 64 + j * 16 + lc;
                for (int r = 0; r < 4; ++r)
                    sS[col][mrow + r] = f2bf(fmaxf(accH[i][j][r], 0.f) * dv[i][r]);
            }
        __syncthreads();
        unsigned short* Ob = OutT + (size_t)b * DF * M_ + mt * 128;
        for (int it = 0; it < 8; ++it) {
            int c = t + 256 * it;
            int orow = c >> 4, off = (c & 15) * 8;
            *(short8*)(Ob + (size_t)orow * M_ + off) = *(const short8*)(&sS[orow][off]);
        }
    }
}

// ---------------------------------------------------------------- launch
extern "C" void kernel_launch(void* const* d_in, const int* in_sizes, int n_in,
                              void* d_out, int out_size, void* d_ws, size_t ws_size,
                              hipStream_t stream) {
    (void)in_sizes; (void)n_in; (void)out_size;
    const float* X  = (const float*)d_in[0];
    const float* E  = (const float*)d_in[1];
    const float* W1 = (const float*)d_in[2];
    const float* W2 = (const float*)d_in[3];
    float* out = (float*)d_out;

    char* ws = (char*)d_ws;
    unsigned short* Ebf  = (unsigned short*)(ws);
    unsigned short* W1bf = (unsigned short*)(ws + 4194304);
    unsigned short* W2bf = (unsigned short*)(ws + 4227072);
    float*          dinv = (float*)(ws + 4259840);
    unsigned short* Xt   = (unsigned short*)(ws + 4390912);
    unsigned short* Ht   = (unsigned short*)(ws + 12779520);
    const size_t NEED = 21168128ull;          // Ebf..Ht end; no S matrix anymore

    if (ws_size >= NEED) {
        prep_kernel<<<dim3(16, 32), 256, 0, stream>>>(E, X, Ebf, dinv, Xt);
        layer_kernel<1><<<dim3(16, 32), 256, 0, stream>>>(Ebf, Xt, W1, dinv, Ht, nullptr);
        layer_kernel<2><<<dim3(16, 32), 256, 0, stream>>>(Ebf, Ht, W2, dinv, nullptr, out);
    } else {
        cast_kernel<<<2080, 256, 0, stream>>>(E, W1, W2, Ebf, W1bf, W2bf);
        degree_kernel<<<dim3(8, 32), 256, 0, stream>>>(Ebf, dinv);
        tscale128_kernel<<<dim3(8, 32), 256, 0, stream>>>(X, dinv, Xt);
        gcn_kernel<1><<<dim3(8, 32), 256, 0, stream>>>(Ebf, Xt, W1bf, dinv, Ht, nullptr);
        gcn_kernel<2><<<dim3(8, 32), 256, 0, stream>>>(Ebf, Ht, W2bf, dinv, nullptr, out);
    }
}